// Round 9
// baseline (12.381 us; speedup 1.0000x reference)
//
#include <hip/hip_runtime.h>

#define CLAMP_MIN 1e-12f
#define CLAMP_MAX 1e12f
#define NB 128    // kernel-1 blocks; 16 waves/block, TWO samples per wave

// Kernel 1: each wave computes clamped squared distances for 2 samples with
// all 8 float4 loads issued before the math (max memory-level parallelism);
// 16 waves/block reduce via LDS to one partial per block.
__global__ void __launch_bounds__(1024) center_dist_part_kernel(
    const float* __restrict__ x,
    const float* __restrict__ centers,
    const int* __restrict__ labels,
    float* __restrict__ partials,
    int batch, int feat) {
    const int wave = threadIdx.x >> 6;
    const int lane = threadIdx.x & 63;
    const int i0 = (blockIdx.x * 16 + wave) * 2;   // first sample of the pair
    const int i1 = i0 + 1;

    __shared__ float swave[16];

    float pair = 0.0f;
    if (i1 < batch && feat == 512) {
        const float* xr0 = x + (size_t)i0 * feat;
        const float* cr0 = centers + (size_t)labels[i0] * feat;
        const float* xr1 = x + (size_t)i1 * feat;
        const float* cr1 = centers + (size_t)labels[i1] * feat;
        const int k0 = lane * 4;
        // Issue all 8 loads first (independent -> deep in flight).
        const float4 xa0 = *reinterpret_cast<const float4*>(xr0 + k0);
        const float4 xa1 = *reinterpret_cast<const float4*>(xr0 + k0 + 256);
        const float4 ca0 = *reinterpret_cast<const float4*>(cr0 + k0);
        const float4 ca1 = *reinterpret_cast<const float4*>(cr0 + k0 + 256);
        const float4 xb0 = *reinterpret_cast<const float4*>(xr1 + k0);
        const float4 xb1 = *reinterpret_cast<const float4*>(xr1 + k0 + 256);
        const float4 cb0 = *reinterpret_cast<const float4*>(cr1 + k0);
        const float4 cb1 = *reinterpret_cast<const float4*>(cr1 + k0 + 256);

        float a = 0.0f, b = 0.0f;
        {
            const float d0 = xa0.x - ca0.x, d1 = xa0.y - ca0.y;
            const float d2 = xa0.z - ca0.z, d3 = xa0.w - ca0.w;
            const float d4 = xa1.x - ca1.x, d5 = xa1.y - ca1.y;
            const float d6 = xa1.z - ca1.z, d7 = xa1.w - ca1.w;
            a = d0 * d0 + d1 * d1 + d2 * d2 + d3 * d3
              + d4 * d4 + d5 * d5 + d6 * d6 + d7 * d7;
        }
        {
            const float d0 = xb0.x - cb0.x, d1 = xb0.y - cb0.y;
            const float d2 = xb0.z - cb0.z, d3 = xb0.w - cb0.w;
            const float d4 = xb1.x - cb1.x, d5 = xb1.y - cb1.y;
            const float d6 = xb1.z - cb1.z, d7 = xb1.w - cb1.w;
            b = d0 * d0 + d1 * d1 + d2 * d2 + d3 * d3
              + d4 * d4 + d5 * d5 + d6 * d6 + d7 * d7;
        }
        // Reduce both samples; clamp each AFTER its own full wave-sum.
        #pragma unroll
        for (int off = 32; off > 0; off >>= 1) {
            a += __shfl_down(a, off);
            b += __shfl_down(b, off);
        }
        if (lane == 0) {
            pair = fminf(fmaxf(a, CLAMP_MIN), CLAMP_MAX)
                 + fminf(fmaxf(b, CLAMP_MIN), CLAMP_MAX);
        }
    } else {
        // Generic fallback (handles tail / other feat sizes).
        for (int s = i0; s <= i1 && s < batch; ++s) {
            const float* xr = x + (size_t)s * feat;
            const float* cr = centers + (size_t)labels[s] * feat;
            float p = 0.0f;
            for (int k = lane * 4; k < feat; k += 64 * 4) {
                const float4 xv = *reinterpret_cast<const float4*>(xr + k);
                const float4 cv = *reinterpret_cast<const float4*>(cr + k);
                const float dx = xv.x - cv.x, dy = xv.y - cv.y;
                const float dz = xv.z - cv.z, dw = xv.w - cv.w;
                p += dx * dx + dy * dy + dz * dz + dw * dw;
            }
            #pragma unroll
            for (int off = 32; off > 0; off >>= 1) p += __shfl_down(p, off);
            if (lane == 0) pair += fminf(fmaxf(p, CLAMP_MIN), CLAMP_MAX);
        }
    }

    if (lane == 0) swave[wave] = pair;
    __syncthreads();

    if (threadIdx.x < 64) {
        float v = (lane < 16) ? swave[lane] : 0.0f;
        #pragma unroll
        for (int off = 8; off > 0; off >>= 1) v += __shfl_down(v, off);
        if (lane == 0) partials[blockIdx.x] = v;
    }
}

// Kernel 2: single wave, one float2 per lane (NB=128 partials).
__global__ void __launch_bounds__(64) mean_kernel(
    const float* __restrict__ partials,
    float* __restrict__ out,
    int batch) {
    const int lane = threadIdx.x;
    const float2 v = reinterpret_cast<const float2*>(partials)[lane];
    float s = v.x + v.y;
    #pragma unroll
    for (int off = 32; off > 0; off >>= 1) s += __shfl_down(s, off);
    if (lane == 0) out[0] = s / (float)batch;
}

extern "C" void kernel_launch(void* const* d_in, const int* in_sizes, int n_in,
                              void* d_out, int out_size, void* d_ws, size_t ws_size,
                              hipStream_t stream) {
    const float* x       = (const float*)d_in[0];
    const float* centers = (const float*)d_in[1];
    const int*   labels  = (const int*)d_in[2];
    float* out = (float*)d_out;

    const int batch = in_sizes[2];             // 4096
    const int feat  = in_sizes[0] / batch;     // 512

    float* partials = (float*)d_ws;            // NB floats

    center_dist_part_kernel<<<NB, 1024, 0, stream>>>(
        x, centers, labels, partials, batch, feat);
    mean_kernel<<<1, 64, 0, stream>>>(partials, out, batch);
}

// Round 10
// 10.905 us; speedup vs baseline: 1.1354x; 1.1354x over previous
//
#include <hip/hip_runtime.h>

#define CLAMP_MIN 1e-12f
#define CLAMP_MAX 1e12f
#define NB 256    // kernel-1 blocks; 8 waves/block, TWO samples per wave

// Kernel 1: 256 blocks x 512 threads. Each wave computes clamped squared
// distances for 2 samples, issuing all 8 independent float4 loads before any
// math (deep MLP); 8 waves/block reduce via LDS to one partial per block.
// Full 256-CU coverage (the round-9 mistake was 128 blocks = half the chip).
__global__ void __launch_bounds__(512) center_dist_part_kernel(
    const float* __restrict__ x,
    const float* __restrict__ centers,
    const int* __restrict__ labels,
    float* __restrict__ partials,
    int batch, int feat) {
    const int wave = threadIdx.x >> 6;      // 0..7
    const int lane = threadIdx.x & 63;
    const int i0 = (blockIdx.x * 8 + wave) * 2;   // first sample of the pair
    const int i1 = i0 + 1;

    __shared__ float swave[8];

    float pair = 0.0f;
    if (i1 < batch && feat == 512) {
        const float* xr0 = x + (size_t)i0 * feat;
        const float* cr0 = centers + (size_t)labels[i0] * feat;
        const float* xr1 = x + (size_t)i1 * feat;
        const float* cr1 = centers + (size_t)labels[i1] * feat;
        const int k0 = lane * 4;
        // Issue all 8 loads first (independent -> deep in flight).
        const float4 xa0 = *reinterpret_cast<const float4*>(xr0 + k0);
        const float4 xa1 = *reinterpret_cast<const float4*>(xr0 + k0 + 256);
        const float4 ca0 = *reinterpret_cast<const float4*>(cr0 + k0);
        const float4 ca1 = *reinterpret_cast<const float4*>(cr0 + k0 + 256);
        const float4 xb0 = *reinterpret_cast<const float4*>(xr1 + k0);
        const float4 xb1 = *reinterpret_cast<const float4*>(xr1 + k0 + 256);
        const float4 cb0 = *reinterpret_cast<const float4*>(cr1 + k0);
        const float4 cb1 = *reinterpret_cast<const float4*>(cr1 + k0 + 256);

        float a, b;
        {
            const float d0 = xa0.x - ca0.x, d1 = xa0.y - ca0.y;
            const float d2 = xa0.z - ca0.z, d3 = xa0.w - ca0.w;
            const float d4 = xa1.x - ca1.x, d5 = xa1.y - ca1.y;
            const float d6 = xa1.z - ca1.z, d7 = xa1.w - ca1.w;
            a = d0 * d0 + d1 * d1 + d2 * d2 + d3 * d3
              + d4 * d4 + d5 * d5 + d6 * d6 + d7 * d7;
        }
        {
            const float d0 = xb0.x - cb0.x, d1 = xb0.y - cb0.y;
            const float d2 = xb0.z - cb0.z, d3 = xb0.w - cb0.w;
            const float d4 = xb1.x - cb1.x, d5 = xb1.y - cb1.y;
            const float d6 = xb1.z - cb1.z, d7 = xb1.w - cb1.w;
            b = d0 * d0 + d1 * d1 + d2 * d2 + d3 * d3
              + d4 * d4 + d5 * d5 + d6 * d6 + d7 * d7;
        }
        // Reduce both samples; clamp each AFTER its full wave-sum.
        #pragma unroll
        for (int off = 32; off > 0; off >>= 1) {
            a += __shfl_down(a, off);
            b += __shfl_down(b, off);
        }
        if (lane == 0) {
            pair = fminf(fmaxf(a, CLAMP_MIN), CLAMP_MAX)
                 + fminf(fmaxf(b, CLAMP_MIN), CLAMP_MAX);
        }
    } else {
        // Generic fallback (tail / other feat sizes).
        for (int s = i0; s <= i1 && s < batch; ++s) {
            const float* xr = x + (size_t)s * feat;
            const float* cr = centers + (size_t)labels[s] * feat;
            float p = 0.0f;
            for (int k = lane * 4; k < feat; k += 64 * 4) {
                const float4 xv = *reinterpret_cast<const float4*>(xr + k);
                const float4 cv = *reinterpret_cast<const float4*>(cr + k);
                const float dx = xv.x - cv.x, dy = xv.y - cv.y;
                const float dz = xv.z - cv.z, dw = xv.w - cv.w;
                p += dx * dx + dy * dy + dz * dz + dw * dw;
            }
            #pragma unroll
            for (int off = 32; off > 0; off >>= 1) p += __shfl_down(p, off);
            if (lane == 0) pair += fminf(fmaxf(p, CLAMP_MIN), CLAMP_MAX);
        }
    }

    if (lane == 0) swave[wave] = pair;
    __syncthreads();

    if (threadIdx.x < 64) {
        float v = (lane < 8) ? swave[lane] : 0.0f;
        #pragma unroll
        for (int off = 4; off > 0; off >>= 1) v += __shfl_down(v, off);
        if (lane == 0) partials[blockIdx.x] = v;
    }
}

// Kernel 2: single wave, one float4 per lane (NB=256 partials).
__global__ void __launch_bounds__(64) mean_kernel(
    const float* __restrict__ partials,
    float* __restrict__ out,
    int batch) {
    const int lane = threadIdx.x;
    const float4 v = reinterpret_cast<const float4*>(partials)[lane];
    float s = v.x + v.y + v.z + v.w;
    #pragma unroll
    for (int off = 32; off > 0; off >>= 1) s += __shfl_down(s, off);
    if (lane == 0) out[0] = s / (float)batch;
}

extern "C" void kernel_launch(void* const* d_in, const int* in_sizes, int n_in,
                              void* d_out, int out_size, void* d_ws, size_t ws_size,
                              hipStream_t stream) {
    const float* x       = (const float*)d_in[0];
    const float* centers = (const float*)d_in[1];
    const int*   labels  = (const int*)d_in[2];
    float* out = (float*)d_out;

    const int batch = in_sizes[2];             // 4096
    const int feat  = in_sizes[0] / batch;     // 512

    float* partials = (float*)d_ws;            // NB floats

    center_dist_part_kernel<<<NB, 512, 0, stream>>>(
        x, centers, labels, partials, batch, feat);
    mean_kernel<<<1, 64, 0, stream>>>(partials, out, batch);
}

// Round 11
// 10.904 us; speedup vs baseline: 1.1354x; 1.0000x over previous
//
#include <hip/hip_runtime.h>

#define CLAMP_MIN 1e-12f
#define CLAMP_MAX 1e12f
#define NB 256    // kernel-1 blocks; 4 waves/block, FOUR samples per wave

// Kernel 1: 256 blocks x 256 threads. Each wave computes clamped squared
// distances for 4 samples, issuing all 16 independent float4 loads before
// any math (maximum memory-level parallelism at full 256-CU coverage);
// 4 waves/block reduce via LDS to one partial per block.
__global__ void __launch_bounds__(256) center_dist_part_kernel(
    const float* __restrict__ x,
    const float* __restrict__ centers,
    const int* __restrict__ labels,
    float* __restrict__ partials,
    int batch, int feat) {
    const int wave = threadIdx.x >> 6;      // 0..3
    const int lane = threadIdx.x & 63;
    const int i0 = (blockIdx.x * 4 + wave) * 4;   // first sample of the quad

    __shared__ float swave[4];

    float quad = 0.0f;
    if (i0 + 3 < batch && feat == 512) {
        const int k0 = lane * 4;
        const float* xr0 = x + (size_t)(i0 + 0) * feat;
        const float* xr1 = x + (size_t)(i0 + 1) * feat;
        const float* xr2 = x + (size_t)(i0 + 2) * feat;
        const float* xr3 = x + (size_t)(i0 + 3) * feat;
        const float* cr0 = centers + (size_t)labels[i0 + 0] * feat;
        const float* cr1 = centers + (size_t)labels[i0 + 1] * feat;
        const float* cr2 = centers + (size_t)labels[i0 + 2] * feat;
        const float* cr3 = centers + (size_t)labels[i0 + 3] * feat;

        // Issue all 16 loads first (independent -> deep in flight).
        const float4 xa0 = *reinterpret_cast<const float4*>(xr0 + k0);
        const float4 xa1 = *reinterpret_cast<const float4*>(xr0 + k0 + 256);
        const float4 xb0 = *reinterpret_cast<const float4*>(xr1 + k0);
        const float4 xb1 = *reinterpret_cast<const float4*>(xr1 + k0 + 256);
        const float4 xc0 = *reinterpret_cast<const float4*>(xr2 + k0);
        const float4 xc1 = *reinterpret_cast<const float4*>(xr2 + k0 + 256);
        const float4 xd0 = *reinterpret_cast<const float4*>(xr3 + k0);
        const float4 xd1 = *reinterpret_cast<const float4*>(xr3 + k0 + 256);
        const float4 ca0 = *reinterpret_cast<const float4*>(cr0 + k0);
        const float4 ca1 = *reinterpret_cast<const float4*>(cr0 + k0 + 256);
        const float4 cb0 = *reinterpret_cast<const float4*>(cr1 + k0);
        const float4 cb1 = *reinterpret_cast<const float4*>(cr1 + k0 + 256);
        const float4 cc0 = *reinterpret_cast<const float4*>(cr2 + k0);
        const float4 cc1 = *reinterpret_cast<const float4*>(cr2 + k0 + 256);
        const float4 cd0 = *reinterpret_cast<const float4*>(cr3 + k0);
        const float4 cd1 = *reinterpret_cast<const float4*>(cr3 + k0 + 256);

        float a, b, c, d;
        {
            const float d0 = xa0.x - ca0.x, d1 = xa0.y - ca0.y;
            const float d2 = xa0.z - ca0.z, d3 = xa0.w - ca0.w;
            const float d4 = xa1.x - ca1.x, d5 = xa1.y - ca1.y;
            const float d6 = xa1.z - ca1.z, d7 = xa1.w - ca1.w;
            a = d0 * d0 + d1 * d1 + d2 * d2 + d3 * d3
              + d4 * d4 + d5 * d5 + d6 * d6 + d7 * d7;
        }
        {
            const float d0 = xb0.x - cb0.x, d1 = xb0.y - cb0.y;
            const float d2 = xb0.z - cb0.z, d3 = xb0.w - cb0.w;
            const float d4 = xb1.x - cb1.x, d5 = xb1.y - cb1.y;
            const float d6 = xb1.z - cb1.z, d7 = xb1.w - cb1.w;
            b = d0 * d0 + d1 * d1 + d2 * d2 + d3 * d3
              + d4 * d4 + d5 * d5 + d6 * d6 + d7 * d7;
        }
        {
            const float d0 = xc0.x - cc0.x, d1 = xc0.y - cc0.y;
            const float d2 = xc0.z - cc0.z, d3 = xc0.w - cc0.w;
            const float d4 = xc1.x - cc1.x, d5 = xc1.y - cc1.y;
            const float d6 = xc1.z - cc1.z, d7 = xc1.w - cc1.w;
            c = d0 * d0 + d1 * d1 + d2 * d2 + d3 * d3
              + d4 * d4 + d5 * d5 + d6 * d6 + d7 * d7;
        }
        {
            const float d0 = xd0.x - cd0.x, d1 = xd0.y - cd0.y;
            const float d2 = xd0.z - cd0.z, d3 = xd0.w - cd0.w;
            const float d4 = xd1.x - cd1.x, d5 = xd1.y - cd1.y;
            const float d6 = xd1.z - cd1.z, d7 = xd1.w - cd1.w;
            d = d0 * d0 + d1 * d1 + d2 * d2 + d3 * d3
              + d4 * d4 + d5 * d5 + d6 * d6 + d7 * d7;
        }
        // Four independent wave-sum chains; clamp each AFTER its full sum.
        #pragma unroll
        for (int off = 32; off > 0; off >>= 1) {
            a += __shfl_down(a, off);
            b += __shfl_down(b, off);
            c += __shfl_down(c, off);
            d += __shfl_down(d, off);
        }
        if (lane == 0) {
            quad = fminf(fmaxf(a, CLAMP_MIN), CLAMP_MAX)
                 + fminf(fmaxf(b, CLAMP_MIN), CLAMP_MAX)
                 + fminf(fmaxf(c, CLAMP_MIN), CLAMP_MAX)
                 + fminf(fmaxf(d, CLAMP_MIN), CLAMP_MAX);
        }
    } else {
        // Generic fallback (tail / other feat sizes).
        for (int s = i0; s < i0 + 4 && s < batch; ++s) {
            const float* xr = x + (size_t)s * feat;
            const float* cr = centers + (size_t)labels[s] * feat;
            float p = 0.0f;
            for (int k = lane * 4; k < feat; k += 64 * 4) {
                const float4 xv = *reinterpret_cast<const float4*>(xr + k);
                const float4 cv = *reinterpret_cast<const float4*>(cr + k);
                const float dx = xv.x - cv.x, dy = xv.y - cv.y;
                const float dz = xv.z - cv.z, dw = xv.w - cv.w;
                p += dx * dx + dy * dy + dz * dz + dw * dw;
            }
            #pragma unroll
            for (int off = 32; off > 0; off >>= 1) p += __shfl_down(p, off);
            if (lane == 0) quad += fminf(fmaxf(p, CLAMP_MIN), CLAMP_MAX);
        }
    }

    if (lane == 0) swave[wave] = quad;
    __syncthreads();

    if (threadIdx.x < 64) {
        float v = (lane < 4) ? swave[lane] : 0.0f;
        #pragma unroll
        for (int off = 2; off > 0; off >>= 1) v += __shfl_down(v, off);
        if (lane == 0) partials[blockIdx.x] = v;
    }
}

// Kernel 2: single wave, one float4 per lane (NB=256 partials).
__global__ void __launch_bounds__(64) mean_kernel(
    const float* __restrict__ partials,
    float* __restrict__ out,
    int batch) {
    const int lane = threadIdx.x;
    const float4 v = reinterpret_cast<const float4*>(partials)[lane];
    float s = v.x + v.y + v.z + v.w;
    #pragma unroll
    for (int off = 32; off > 0; off >>= 1) s += __shfl_down(s, off);
    if (lane == 0) out[0] = s / (float)batch;
}

extern "C" void kernel_launch(void* const* d_in, const int* in_sizes, int n_in,
                              void* d_out, int out_size, void* d_ws, size_t ws_size,
                              hipStream_t stream) {
    const float* x       = (const float*)d_in[0];
    const float* centers = (const float*)d_in[1];
    const int*   labels  = (const int*)d_in[2];
    float* out = (float*)d_out;

    const int batch = in_sizes[2];             // 4096
    const int feat  = in_sizes[0] / batch;     // 512

    float* partials = (float*)d_ws;            // NB floats

    center_dist_part_kernel<<<NB, 256, 0, stream>>>(
        x, centers, labels, partials, batch, feat);
    mean_kernel<<<1, 64, 0, stream>>>(partials, out, batch);
}